// Round 1
// baseline (558.952 us; speedup 1.0000x reference)
//
#include <hip/hip_runtime.h>

#define NBLK 24
#define BATCH 256
#define CCH 32
#define TQ 256
#define TQO 257
#define NCOMP 32         // compute workgroups
#define BPG 8            // batches per compute workgroup (NCOMP*BPG == BATCH)
#define ROWS_PER_WG 16   // rows per copy workgroup (rows = NBLK*BATCH*CCH)

__global__ __launch_bounds__(256) void w2w_kernel(
    const float* __restrict__ qin,
    const float* __restrict__ x,
    const float* __restrict__ num,
    const int*   __restrict__ cat,
    const float* __restrict__ emb,
    const float* __restrict__ W_in,  const float* __restrict__ b_in,
    const float* __restrict__ W_conv,const float* __restrict__ b_conv,
    const float* __restrict__ W_res, const float* __restrict__ b_res,
    const float* __restrict__ W_skip,const float* __restrict__ b_skip,
    const float* __restrict__ W_o1,  const float* __restrict__ b_o1,
    const float* __restrict__ W_o2,  const float* __restrict__ b_o2,
    float* __restrict__ out, float* __restrict__ qout)
{
    const int tid = threadIdx.x;

    if (blockIdx.x >= NCOMP) {
        // ---------------- bulk copy: queues -> new_queues[:, :, :, 0:256] ----------------
        const int wg = blockIdx.x - NCOMP;
        const int row_base = wg * ROWS_PER_WG;
        const int rsub = tid >> 6;   // 0..3 (4 rows per slab)
        const int t4   = tid & 63;   // 64 float4 per 256-float row
        #pragma unroll
        for (int rr = 0; rr < ROWS_PER_WG; rr += 4) {
            const int r = row_base + rr + rsub;
            const float4 v = *(const float4*)(qin + (size_t)r * TQ + t4 * 4);
            float* dst = qout + (size_t)r * TQO + t4 * 4;
            dst[0] = v.x; dst[1] = v.y; dst[2] = v.z; dst[3] = v.w;
        }
        return;
    }

    // ---------------- recurrent chain: 8 batches per WG, 32 threads per batch ----------------
    __shared__ float s_tap[BPG][CCH + 1];
    __shared__ float s_cur[BPG][CCH + 1];
    __shared__ float s_g  [BPG][CCH + 1];
    __shared__ float s_sk [BPG][CCH + 1];

    const int bl = tid >> 5;          // batch-local 0..7
    const int j  = tid & 31;          // channel / output index 0..31
    const int b  = blockIdx.x * BPG + bl;

    // input vector: [x(1), num(8), emb(16)] = 25
    float inp[25];
    inp[0] = x[b];
    #pragma unroll
    for (int k = 0; k < 8; ++k) inp[1 + k] = num[b * 8 + k];
    const int ci = cat[b];
    #pragma unroll
    for (int k = 0; k < 16; ++k) inp[9 + k] = emb[ci * 16 + k];

    // cur = W_in @ inp + b_in    (thread j holds channel j)
    float cur = b_in[j];
    #pragma unroll
    for (int c = 0; c < 25; ++c) cur = fmaf(W_in[j * 25 + c], inp[c], cur);

    // h accumulator for the 128-wide hidden layer: thread j owns m = j, j+32, j+64, j+96
    float h0 = 0.f, h1 = 0.f, h2 = 0.f, h3 = 0.f;

    for (int i = 0; i < NBLK; ++i) {
        const int d = 1 << (i & 7);
        // tap0 always falls inside the old queue: index 256-d in the 257-long q
        const float tap0 = qin[((size_t)(i * BATCH + b) * CCH + j) * TQ + (TQ - d)];

        s_tap[bl][j] = tap0;
        s_cur[bl][j] = cur;
        __syncthreads();

        // z[j], z[j+32]
        float z0 = b_conv[i * 2 * CCH + j];
        float z1 = b_conv[i * 2 * CCH + CCH + j];
        const float* wc0 = W_conv + (size_t)(i * 2 * CCH + j)       * CCH * 2;
        const float* wc1 = W_conv + (size_t)(i * 2 * CCH + CCH + j) * CCH * 2;
        #pragma unroll
        for (int c = 0; c < CCH; ++c) {
            const float t0 = s_tap[bl][c];
            const float t1 = s_cur[bl][c];
            z0 = fmaf(t0, wc0[c * 2], z0);
            z0 = fmaf(t1, wc0[c * 2 + 1], z0);
            z1 = fmaf(t0, wc1[c * 2], z1);
            z1 = fmaf(t1, wc1[c * 2 + 1], z1);
        }
        const float g = tanhf(z0) * (1.f / (1.f + __expf(-z1)));

        // append tap1 (= cur before update) into the new queue column 256
        qout[((size_t)(i * BATCH + b) * CCH + j) * TQO + TQ] = cur;

        s_g[bl][j] = g;
        __syncthreads();

        // skip[j] and residual cur_new[j]
        float sk = b_skip[i * CCH + j];
        float cn = b_res[i * CCH + j] + cur;   // + tap1
        const float* ws = W_skip + (size_t)(i * CCH + j) * CCH;
        const float* wr = W_res  + (size_t)(i * CCH + j) * CCH;
        #pragma unroll
        for (int k = 0; k < CCH; ++k) {
            const float gk = s_g[bl][k];
            sk = fmaf(gk, ws[k], sk);
            cn = fmaf(gk, wr[k], cn);
        }
        s_sk[bl][j] = fmaxf(sk, 0.f);   // relu(concat(skips)) applied per-element
        cur = cn;
        __syncthreads();

        // fold this block's 32 skip channels into h[128]
        const float* wo1 = W_o1 + i * CCH;   // W_o1[m*768 + i*32 + s]
        #pragma unroll
        for (int s = 0; s < CCH; ++s) {
            const float rs = s_sk[bl][s];
            h0 = fmaf(rs, wo1[(j)      * (NBLK * CCH) + s], h0);
            h1 = fmaf(rs, wo1[(j + 32) * (NBLK * CCH) + s], h1);
            h2 = fmaf(rs, wo1[(j + 64) * (NBLK * CCH) + s], h2);
            h3 = fmaf(rs, wo1[(j + 96) * (NBLK * CCH) + s], h3);
        }
        // next iteration's s_tap/s_cur writes are fenced by the barrier above
    }

    // final MLP: relu(h + b_o1) @ W_o2 + b_o2
    float p = 0.f;
    p = fmaf(fmaxf(h0 + b_o1[j],      0.f), W_o2[j],      p);
    p = fmaf(fmaxf(h1 + b_o1[j + 32], 0.f), W_o2[j + 32], p);
    p = fmaf(fmaxf(h2 + b_o1[j + 64], 0.f), W_o2[j + 64], p);
    p = fmaf(fmaxf(h3 + b_o1[j + 96], 0.f), W_o2[j + 96], p);
    // reduce over the 32 lanes of this batch (xor masks < 32 stay in-half)
    #pragma unroll
    for (int m = 16; m >= 1; m >>= 1) p += __shfl_xor(p, m);
    if (j == 0) out[b] = p + b_o2[0];
}

extern "C" void kernel_launch(void* const* d_in, const int* in_sizes, int n_in,
                              void* d_out, int out_size, void* d_ws, size_t ws_size,
                              hipStream_t stream) {
    const float* qin    = (const float*)d_in[0];
    const float* x      = (const float*)d_in[1];
    const float* num    = (const float*)d_in[2];
    const int*   cat    = (const int*)  d_in[3];
    const float* emb    = (const float*)d_in[4];
    const float* W_in   = (const float*)d_in[5];
    const float* b_in   = (const float*)d_in[6];
    const float* W_conv = (const float*)d_in[7];
    const float* b_conv = (const float*)d_in[8];
    const float* W_res  = (const float*)d_in[9];
    const float* b_res  = (const float*)d_in[10];
    const float* W_skip = (const float*)d_in[11];
    const float* b_skip = (const float*)d_in[12];
    const float* W_o1   = (const float*)d_in[13];
    const float* b_o1   = (const float*)d_in[14];
    const float* W_o2   = (const float*)d_in[15];
    const float* b_o2   = (const float*)d_in[16];

    float* out  = (float*)d_out;           // (256,1,1)
    float* qout = (float*)d_out + BATCH;   // (24,256,32,257)

    const int rows  = NBLK * BATCH * CCH;          // 196608
    const int ncopy = rows / ROWS_PER_WG;          // 12288
    dim3 grid(NCOMP + ncopy), block(256);
    hipLaunchKernelGGL(w2w_kernel, grid, block, 0, stream,
                       qin, x, num, cat, emb, W_in, b_in, W_conv, b_conv,
                       W_res, b_res, W_skip, b_skip, W_o1, b_o1, W_o2, b_o2,
                       out, qout);
}

// Round 2
// 501.214 us; speedup vs baseline: 1.1152x; 1.1152x over previous
//
#include <hip/hip_runtime.h>

#define NBLK 24
#define BATCH 256
#define CCH 32
#define TQ 256
#define TQO 257
#define NCOMP 32          // compute workgroups (8 batches each)
#define BPG 8
#define NCOPY 3072        // copy workgroups; 4 waves each; 16 rows/wave
#define ROWS (NBLK*BATCH*CCH)

typedef float f4a4  __attribute__((ext_vector_type(4), aligned(4)));
typedef float f4a16 __attribute__((ext_vector_type(4)));

__global__ __launch_bounds__(256) void w2w_kernel(
    const float* __restrict__ qin,
    const float* __restrict__ x,
    const float* __restrict__ num,
    const int*   __restrict__ cat,
    const float* __restrict__ emb,
    const float* __restrict__ W_in,  const float* __restrict__ b_in,
    const float* __restrict__ W_conv,const float* __restrict__ b_conv,
    const float* __restrict__ W_res, const float* __restrict__ b_res,
    const float* __restrict__ W_skip,const float* __restrict__ b_skip,
    const float* __restrict__ W_o1,  const float* __restrict__ b_o1,
    const float* __restrict__ W_o2,  const float* __restrict__ b_o2,
    float* __restrict__ out, float* __restrict__ qout)
{
    __shared__ __align__(16) float smem[11264];
    const int tid = threadIdx.x;

    if (blockIdx.x >= NCOMP) {
        // ---- bulk copy: qout[r][0:256] = qin[r][0:256], 16B-ALIGNED stores ----
        const int wid  = (blockIdx.x - NCOMP) * 4 + (tid >> 6);
        const int lane = tid & 63;
        size_t r = (size_t)wid * 16;
        for (int rr = 0; rr < 16; ++rr, ++r) {
            const size_t sb = r * TQ, db = r * TQO;
            const int a = (4 - ((int)r & 3)) & 3;        // head so dst f4s are aligned
            if (lane < 63) {
                f4a4 v = *(const f4a4*)(qin + sb + a + 4 * lane);   // align-4 load
                *(f4a16*)(qout + db + a + 4 * lane) = v;            // aligned store
            } else {
                #pragma unroll
                for (int e = 0; e < 4; ++e) {
                    const int f = (e < a) ? e : e + 252;
                    qout[db + f] = qin[sb + f];
                }
            }
        }
        return;
    }

    // ---------------- compute: 8 batches/WG, 32 lanes/batch ----------------
    float* s_wc = smem;            // [0,4096)   W_conv[i]: row m(0..63) x 64
    float* s_wr = smem + 4096;     // [4096,5120) row j x 32
    float* s_ws = smem + 5120;     // [5120,6144)
    float* s_wo = smem + 6144;     // [6144,10240) row m(0..127) x 32 (slice cols i*32..)
    float* s_tc = smem + 10240;    // 8 x 64  (interleaved tap,cur)
    float* s_g  = smem + 10752;    // 8 x 32
    float* s_sk = smem + 11008;    // 8 x 32

    const int bl = tid >> 5;
    const int j  = tid & 31;
    const int sw = j & 7;
    const int b  = blockIdx.x * BPG + bl;

    // prologue: cur = W_in @ [x,num,emb] + b_in
    float cur;
    {
        float acc = b_in[j];
        acc = fmaf(W_in[j * 25 + 0], x[b], acc);
        #pragma unroll
        for (int k = 0; k < 8; ++k) acc = fmaf(W_in[j * 25 + 1 + k], num[b * 8 + k], acc);
        const int ci = cat[b];
        #pragma unroll
        for (int k = 0; k < 16; ++k) acc = fmaf(W_in[j * 25 + 9 + k], emb[ci * 16 + k], acc);
        cur = acc;
    }

    float h0 = 0.f, h1 = 0.f, h2 = 0.f, h3 = 0.f;
    f4a16 rg[10];

    // cooperative weight staging: all LDS-linear, granule-spread (t&7)
    auto issue = [&](int i) {
        const float* pc = W_conv + (size_t)i * 4096;
        #pragma unroll
        for (int k = 0; k < 4; ++k) rg[k] = *(const f4a16*)(pc + (size_t)(tid + 256 * k) * 4);
        rg[4] = *(const f4a16*)(W_res  + (size_t)i * 1024 + tid * 4);
        rg[5] = *(const f4a16*)(W_skip + (size_t)i * 1024 + tid * 4);
        #pragma unroll
        for (int k = 0; k < 4; ++k) {
            const int fi = tid + 256 * k;              // f4 index 0..1023
            const int m = fi >> 3, p = fi & 7;
            rg[6 + k] = *(const f4a16*)(W_o1 + (size_t)m * 768 + (size_t)i * 32 + p * 4);
        }
    };
    auto commit = [&]() {
        #pragma unroll
        for (int k = 0; k < 4; ++k) *(f4a16*)(s_wc + (tid + 256 * k) * 4) = rg[k];
        *(f4a16*)(s_wr + tid * 4) = rg[4];
        *(f4a16*)(s_ws + tid * 4) = rg[5];
        #pragma unroll
        for (int k = 0; k < 4; ++k) *(f4a16*)(s_wo + (tid + 256 * k) * 4) = rg[6 + k];
    };

    // stage iter 0 + initial tap/cur
    issue(0);
    {
        const float t0 = qin[((size_t)b * CCH + j) * TQ + (TQ - 1)];   // i=0, d=1
        s_tc[bl * 64 + 2 * j]     = t0;
        s_tc[bl * 64 + 2 * j + 1] = cur;
    }
    commit();
    __syncthreads();

    for (int i = 0; i < NBLK; ++i) {
        if (i + 1 < NBLK) issue(i + 1);
        float tap_nxt = 0.f;
        if (i + 1 < NBLK) {
            const int d = 1 << ((i + 1) & 7);
            tap_nxt = qin[((size_t)((i + 1) * BATCH + b) * CCH + j) * TQ + (TQ - d)];
        }
        const float bc0 = b_conv[i * 64 + j];
        const float bc1 = b_conv[i * 64 + 32 + j];
        const float brj = b_res[i * 32 + j];
        const float bsj = b_skip[i * 32 + j];

        // ---- z = Wc0*tap + Wc1*cur + b  (vector LDS, XOR-swizzled k order) ----
        const f4a16* wr0 = (const f4a16*)(s_wc) + j * 16;
        const f4a16* wr1 = (const f4a16*)(s_wc) + (32 + j) * 16;
        const f4a16* tcv = (const f4a16*)(s_tc) + bl * 16;
        float z0a = 0.f, z0b = 0.f, z1a = 0.f, z1b = 0.f;
        #pragma unroll
        for (int t = 0; t < 16; ++t) {
            const int k = (t & 8) | ((t ^ sw) & 7);
            const f4a16 w0 = wr0[k], w1 = wr1[k], dv = tcv[k];
            z0a = fmaf(w0.x, dv.x, z0a); z0b = fmaf(w0.y, dv.y, z0b);
            z0a = fmaf(w0.z, dv.z, z0a); z0b = fmaf(w0.w, dv.w, z0b);
            z1a = fmaf(w1.x, dv.x, z1a); z1b = fmaf(w1.y, dv.y, z1b);
            z1a = fmaf(w1.z, dv.z, z1a); z1b = fmaf(w1.w, dv.w, z1b);
        }
        const float z0 = z0a + z0b + bc0;
        const float z1 = z1a + z1b + bc1;
        const float g  = tanhf(z0) * (1.f / (1.f + __expf(-z1)));

        // append tap1 (= old cur) into new queue column 256
        qout[((size_t)(i * BATCH + b) * CCH + j) * TQO + TQ] = cur;

        s_g[bl * 32 + j] = g;
        __builtin_amdgcn_wave_barrier();   // subgroup comms are wave-internal; LDS is in-order per wave

        // ---- skip & residual ----
        const f4a16* gv  = (const f4a16*)(s_g)  + bl * 8;
        const f4a16* wsv = (const f4a16*)(s_ws) + j * 8;
        const f4a16* wrv = (const f4a16*)(s_wr) + j * 8;
        float ska = bsj, skb = 0.f, cna = brj + cur, cnb = 0.f;
        #pragma unroll
        for (int t = 0; t < 8; ++t) {
            const int k = (t ^ sw) & 7;
            const f4a16 gk = gv[k], wv = wsv[k], rv = wrv[k];
            ska = fmaf(gk.x, wv.x, ska); skb = fmaf(gk.y, wv.y, skb);
            ska = fmaf(gk.z, wv.z, ska); skb = fmaf(gk.w, wv.w, skb);
            cna = fmaf(gk.x, rv.x, cna); cnb = fmaf(gk.y, rv.y, cnb);
            cna = fmaf(gk.z, rv.z, cna); cnb = fmaf(gk.w, rv.w, cnb);
        }
        const float skr = fmaxf(ska + skb, 0.f);
        cur = cna + cnb;

        s_sk[bl * 32 + j] = skr;
        if (i + 1 < NBLK) {   // next iter's tap/cur (read only after the two barriers below)
            s_tc[bl * 64 + 2 * j]     = tap_nxt;
            s_tc[bl * 64 + 2 * j + 1] = cur;
        }
        __builtin_amdgcn_wave_barrier();

        // ---- fold skips into h[128] ----
        const f4a16* skv = (const f4a16*)(s_sk) + bl * 8;
        const f4a16* o0 = (const f4a16*)(s_wo) + j * 8;
        const f4a16* o1 = (const f4a16*)(s_wo) + (32 + j) * 8;
        const f4a16* o2 = (const f4a16*)(s_wo) + (64 + j) * 8;
        const f4a16* o3 = (const f4a16*)(s_wo) + (96 + j) * 8;
        #pragma unroll
        for (int t = 0; t < 8; ++t) {
            const int k = (t ^ sw) & 7;
            const f4a16 rv = skv[k];
            const f4a16 a0 = o0[k], a1 = o1[k], a2 = o2[k], a3 = o3[k];
            h0 = fmaf(rv.x, a0.x, h0); h0 = fmaf(rv.y, a0.y, h0);
            h0 = fmaf(rv.z, a0.z, h0); h0 = fmaf(rv.w, a0.w, h0);
            h1 = fmaf(rv.x, a1.x, h1); h1 = fmaf(rv.y, a1.y, h1);
            h1 = fmaf(rv.z, a1.z, h1); h1 = fmaf(rv.w, a1.w, h1);
            h2 = fmaf(rv.x, a2.x, h2); h2 = fmaf(rv.y, a2.y, h2);
            h2 = fmaf(rv.z, a2.z, h2); h2 = fmaf(rv.w, a2.w, h2);
            h3 = fmaf(rv.x, a3.x, h3); h3 = fmaf(rv.y, a3.y, h3);
            h3 = fmaf(rv.z, a3.z, h3); h3 = fmaf(rv.w, a3.w, h3);
        }

        __syncthreads();                 // all reads of weights(i) done
        if (i + 1 < NBLK) commit();      // store weights(i+1)
        __syncthreads();                 // staging visible
    }

    // ---- final MLP + reduce ----
    float p = 0.f;
    p = fmaf(fmaxf(h0 + b_o1[j],      0.f), W_o2[j],      p);
    p = fmaf(fmaxf(h1 + b_o1[j + 32], 0.f), W_o2[j + 32], p);
    p = fmaf(fmaxf(h2 + b_o1[j + 64], 0.f), W_o2[j + 64], p);
    p = fmaf(fmaxf(h3 + b_o1[j + 96], 0.f), W_o2[j + 96], p);
    #pragma unroll
    for (int m = 16; m >= 1; m >>= 1) p += __shfl_xor(p, m);
    if (j == 0) out[b] = p + b_o2[0];
}

extern "C" void kernel_launch(void* const* d_in, const int* in_sizes, int n_in,
                              void* d_out, int out_size, void* d_ws, size_t ws_size,
                              hipStream_t stream) {
    const float* qin    = (const float*)d_in[0];
    const float* x      = (const float*)d_in[1];
    const float* num    = (const float*)d_in[2];
    const int*   cat    = (const int*)  d_in[3];
    const float* emb    = (const float*)d_in[4];
    const float* W_in   = (const float*)d_in[5];
    const float* b_in   = (const float*)d_in[6];
    const float* W_conv = (const float*)d_in[7];
    const float* b_conv = (const float*)d_in[8];
    const float* W_res  = (const float*)d_in[9];
    const float* b_res  = (const float*)d_in[10];
    const float* W_skip = (const float*)d_in[11];
    const float* b_skip = (const float*)d_in[12];
    const float* W_o1   = (const float*)d_in[13];
    const float* b_o1   = (const float*)d_in[14];
    const float* W_o2   = (const float*)d_in[15];
    const float* b_o2   = (const float*)d_in[16];

    float* out  = (float*)d_out;
    float* qout = (float*)d_out + BATCH;

    dim3 grid(NCOMP + NCOPY), block(256);
    hipLaunchKernelGGL(w2w_kernel, grid, block, 0, stream,
                       qin, x, num, cat, emb, W_in, b_in, W_conv, b_conv,
                       W_res, b_res, W_skip, b_skip, W_o1, b_o1, W_o2, b_o2,
                       out, qout);
}